// Round 8
// baseline (296.887 us; speedup 1.0000x reference)
//
#include <hip/hip_runtime.h>
#include <math.h>

// STGCN layer: N=50000, E=800000, C_IN=C_OUT=64, T=4, KT=3.
// Round-15: fuse gather+node via LDS handoff (kill the yT round-trip + a
// launch gap). R7 lesson: totals don't track gather micro-deltas — noise in
// gaps/other dispatches is +-5-7us; only structural cuts matter now.
//   zero_pack:   zero cnt; wave-per-node builds xsr bf16 [c][t] (unscaled
//                gather table) from x (cold); block 0 packs Bt + bb.
//   fill_xbp:    fused: fill role (8 edges/thread, 8 atomics in flight) ||
//                pack role (x -> xbp bf16 [t][c] w/ guard rows; ~90MB rides
//                fill's atomic shadow — R4: shadow fits 90MB, not 115).
//   gather_node: block = 4 waves = 64 nodes.
//                Phase A: wave gathers 8 node-pairs (8 independent 512B
//                gathers in flight, LDS-LUT dinv) -> LDS tile
//                ylds[node][t][c], t-stride 72 ush (36dw = 4 mod 32 ->
//                A-frag ds_read_b128 = 2 lanes/bank = conflict-free).
//                Phase B: after barrier, wave = 16 nodes MFMA GEMM; K-block 0
//                A-frags from LDS, temporal K-blocks from xbp (global).
//                Deletes yT write (25MB) + read (25.6MB) + 1 launch.
//                (grid 3128 waves: R1/R2 showed gather invariant to wave
//                 count/occupancy; ~60us = compulsory 25.6MB x 8-XCD
//                 L2-replication fill floor)
// All dense math in bf16 MFMA w/ fp32 accum; aggregation in fp32.

#define CAP 64   // max bucket capacity; Poisson(16) max degree ~45

typedef __attribute__((ext_vector_type(8))) short bf16x8;   // 8 bf16 = 4 VGPRs
typedef __attribute__((ext_vector_type(4))) float f32x4;

__device__ __forceinline__ float bf2f(unsigned short u) {
    union { unsigned int i; float f; } c; c.i = ((unsigned int)u) << 16; return c.f;
}
__device__ __forceinline__ unsigned short f2bf(float f) {
    union { float f; unsigned int i; } c; c.f = f;
    return (unsigned short)((c.i + 0x7FFFu + ((c.i >> 16) & 1u)) >> 16);  // RNE
}

// Grid = wave-per-node (12500 blocks). Duties:
//  - thread gid < N: cnt[gid] = 0
//  - wave n: xsr[n][c] = bf16(x[n][c][t0..3]) (unscaled [c][t] ushort4)
//  - block 0: Bt[o][k] (k<64: Wg[k][o]; k=b*64+c: Wt[o][c][b-1]); bb=bg+bt
__global__ __launch_bounds__(256) void zero_pack_kernel(unsigned* __restrict__ cnt, int N,
                                                        const float* __restrict__ Wg,
                                                        const float* __restrict__ Wt,
                                                        const float* __restrict__ bg,
                                                        const float* __restrict__ bt,
                                                        unsigned short* __restrict__ Bt,
                                                        float* __restrict__ bb,
                                                        const float* __restrict__ x,
                                                        ushort4* __restrict__ xsr) {
    int gid = blockIdx.x * 256 + threadIdx.x;
    if (gid < N) cnt[gid] = 0u;
    int n = gid >> 6;
    int lane = threadIdx.x & 63;
    if (n < N) {
        float4 v = ((const float4*)x)[(size_t)n * 64 + lane];
        ushort4 sv;
        sv.x = f2bf(v.x); sv.y = f2bf(v.y);
        sv.z = f2bf(v.z); sv.w = f2bf(v.w);
        xsr[(size_t)n * 64 + lane] = sv;
    }
    if (blockIdx.x == 0) {
        for (int idx = threadIdx.x; idx < 64 * 256; idx += 256) {
            int o = idx >> 8, k = idx & 255;
            float w;
            if (k < 64) w = Wg[k * 64 + o];
            else { int b = k >> 6, c = k & 63; w = Wt[o * 192 + c * 3 + (b - 1)]; }
            Bt[idx] = f2bf(w);
        }
        if (threadIdx.x < 64) bb[threadIdx.x] = bg[threadIdx.x] + bt[threadIdx.x];
    }
}

// Fused fill + xbp pack. Block roles split by blockIdx:
//  [0, FB):       fill — 8 edges/thread, 8 independent atomics, 8 CSR stores.
//  [FB, FB+XB):   pack — wave per node, lane = channel; xbp [t][c] bf16 with
//                 zero guard rows at t=-1 and t=4 (x re-read is L3-hot).
__global__ __launch_bounds__(256) void fill_xbp_kernel(const int* __restrict__ ei,
                                                       unsigned* __restrict__ cnt,
                                                       int* __restrict__ csr, int E,
                                                       const float* __restrict__ x,
                                                       unsigned short* __restrict__ xbp,
                                                       int N, int FB) {
    if ((int)blockIdx.x < FB) {
        int t = blockIdx.x * 256 + threadIdx.x;
        int stride = FB * 256;
        int s[8]; int d[8]; unsigned slot[8];
        #pragma unroll
        for (int k = 0; k < 8; ++k) {
            int e = t + k * stride;
            bool v = (e < E);
            s[k] = v ? ei[e] : -1;       // row 0: src
            d[k] = v ? ei[E + e] : 0;    // row 1: dst
        }
        #pragma unroll
        for (int k = 0; k < 8; ++k)
            slot[k] = (s[k] >= 0) ? atomicAdd(&cnt[d[k]], 1u) : 0u;
        #pragma unroll
        for (int k = 0; k < 8; ++k)
            if (s[k] >= 0 && slot[k] < CAP)
                csr[(size_t)d[k] * CAP + slot[k]] = s[k];
    } else {
        int bid = blockIdx.x - FB;
        int n = (bid * 256 + threadIdx.x) >> 6;
        int lane = threadIdx.x & 63;
        if (n >= N) return;
        float4 v = ((const float4*)x)[(size_t)n * 64 + lane];
        unsigned short* xb = xbp + (size_t)n * 384;
        xb[lane]           = 0;            // t = -1 guard
        xb[64 + lane]      = f2bf(v.x);    // t = 0
        xb[128 + lane]     = f2bf(v.y);
        xb[192 + lane]     = f2bf(v.z);
        xb[256 + lane]     = f2bf(v.w);
        xb[320 + lane]     = 0;            // t = 4 guard
    }
}

#define LUTN 1024    // deg LUT entries; Poisson(16) max deg ~45, 1024 is safe
#define NB   64      // nodes per gather_node block
#define YST  72      // ushort stride per t-row (144B = 36dw = 4 mod 32 banks)
#define NST  (4*YST) // 288 ushort per node (576B, 16B-aligned)

// Fused gather + node GEMM. Block = 256 threads = 4 waves = NB nodes.
// Phase A: wave w gathers node-pairs p = w, w+4, ... (8 pairs at NB=64):
//   lane = channel c (ushort4 = t0..3); 2 int4 idx loads + 8 independent
//   512B gathers in flight per iter; dinv via LDS LUT; result -> ylds.
// Phase B: wave w = nodes [w*16, w*16+16): 4 groups x 4 nodes, K=256, o=64.
//   A[(n,t)][k]: k<64 -> ylds[nl][t][k] (ds_read_b128, 2-way=free);
//   k=b*64+c -> xbp[n][t+b-1][c] global (guarded rows).
//   B-frag from Bt[o][k] (L2-hot). C/D: col=lane&15 (o), row=(lane>>4)*4+reg.
__global__ __launch_bounds__(256) void gather_node_kernel(const ushort4* __restrict__ xsr,
                                                          const int* __restrict__ csr,
                                                          const unsigned* __restrict__ cnt,
                                                          const unsigned short* __restrict__ xbp,
                                                          const unsigned short* __restrict__ Bt,
                                                          const float* __restrict__ bb,
                                                          float* __restrict__ out, int N) {
    __shared__ float lut[LUTN];
    __shared__ unsigned short ylds[NB * NST];   // 36 KB
    for (int i = threadIdx.x; i < LUTN; i += 256)
        lut[i] = rsqrtf((float)i + 1.0f);
    __syncthreads();

    const int w = threadIdx.x >> 6;
    const int lane = threadIdx.x & 63;
    const int base = blockIdx.x * NB;
    int nb = N - base; if (nb > NB) nb = NB;    // N even -> nb even
    const int npairs = nb >> 1;

    #define DLUT(dv) lut[(dv) < LUTN ? (dv) : LUTN - 1]

    // ---------------- Phase A: gather into LDS ------------------------------
    for (int p = w; p < npairs; p += 4) {
        int nl0 = p * 2, nl1 = nl0 + 1;
        int n0 = base + nl0, n1 = n0 + 1;
        unsigned deg0 = cnt[n0], deg1 = cnt[n1];
        int m0 = (int)deg0; if (m0 > CAP) m0 = CAP;
        int m1 = (int)deg1; if (m1 > CAP) m1 = CAP;
        const int4* r40 = (const int4*)(csr + (size_t)n0 * CAP);
        const int4* r41 = (const int4*)(csr + (size_t)n1 * CAP);
        float di0 = DLUT(deg0), di1 = DLUT(deg1);
        ushort4 s0 = xsr[(size_t)n0 * 64 + lane];
        ushort4 s1 = xsr[(size_t)n1 * 64 + lane];
        float4 acc0 = make_float4(bf2f(s0.x) * di0, bf2f(s0.y) * di0,
                                  bf2f(s0.z) * di0, bf2f(s0.w) * di0);
        float4 acc1 = make_float4(bf2f(s1.x) * di1, bf2f(s1.y) * di1,
                                  bf2f(s1.z) * di1, bf2f(s1.w) * di1);

        int mc = (m0 < m1 ? m0 : m1) & ~3;
        int i = 0;
        for (; i < mc; i += 4) {               // 8 gathers in flight
            int4 a4 = r40[i >> 2];
            int4 b4 = r41[i >> 2];
            float va = DLUT(cnt[a4.x]), vb = DLUT(cnt[a4.y]);
            float vc = DLUT(cnt[a4.z]), vd = DLUT(cnt[a4.w]);
            float ve = DLUT(cnt[b4.x]), vf = DLUT(cnt[b4.y]);
            float vg = DLUT(cnt[b4.z]), vh = DLUT(cnt[b4.w]);
            ushort4 a = xsr[(size_t)a4.x * 64 + lane];
            ushort4 b = xsr[(size_t)a4.y * 64 + lane];
            ushort4 c = xsr[(size_t)a4.z * 64 + lane];
            ushort4 d = xsr[(size_t)a4.w * 64 + lane];
            ushort4 e = xsr[(size_t)b4.x * 64 + lane];
            ushort4 f = xsr[(size_t)b4.y * 64 + lane];
            ushort4 g = xsr[(size_t)b4.z * 64 + lane];
            ushort4 h = xsr[(size_t)b4.w * 64 + lane];
            acc0.x += (bf2f(a.x) * va + bf2f(b.x) * vb) + (bf2f(c.x) * vc + bf2f(d.x) * vd);
            acc0.y += (bf2f(a.y) * va + bf2f(b.y) * vb) + (bf2f(c.y) * vc + bf2f(d.y) * vd);
            acc0.z += (bf2f(a.z) * va + bf2f(b.z) * vb) + (bf2f(c.z) * vc + bf2f(d.z) * vd);
            acc0.w += (bf2f(a.w) * va + bf2f(b.w) * vb) + (bf2f(c.w) * vc + bf2f(d.w) * vd);
            acc1.x += (bf2f(e.x) * ve + bf2f(f.x) * vf) + (bf2f(g.x) * vg + bf2f(h.x) * vh);
            acc1.y += (bf2f(e.y) * ve + bf2f(f.y) * vf) + (bf2f(g.y) * vg + bf2f(h.y) * vh);
            acc1.z += (bf2f(e.z) * ve + bf2f(f.z) * vf) + (bf2f(g.z) * vg + bf2f(h.z) * vh);
            acc1.w += (bf2f(e.w) * ve + bf2f(f.w) * vf) + (bf2f(g.w) * vg + bf2f(h.w) * vh);
        }
        int j = i;
        for (; i + 4 <= m0; i += 4) {          // node0 remainder quads
            int4 a4 = r40[i >> 2];
            float va = DLUT(cnt[a4.x]), vb = DLUT(cnt[a4.y]);
            float vc = DLUT(cnt[a4.z]), vd = DLUT(cnt[a4.w]);
            ushort4 a = xsr[(size_t)a4.x * 64 + lane];
            ushort4 b = xsr[(size_t)a4.y * 64 + lane];
            ushort4 c = xsr[(size_t)a4.z * 64 + lane];
            ushort4 d = xsr[(size_t)a4.w * 64 + lane];
            acc0.x += (bf2f(a.x) * va + bf2f(b.x) * vb) + (bf2f(c.x) * vc + bf2f(d.x) * vd);
            acc0.y += (bf2f(a.y) * va + bf2f(b.y) * vb) + (bf2f(c.y) * vc + bf2f(d.y) * vd);
            acc0.z += (bf2f(a.z) * va + bf2f(b.z) * vb) + (bf2f(c.z) * vc + bf2f(d.z) * vd);
            acc0.w += (bf2f(a.w) * va + bf2f(b.w) * vb) + (bf2f(c.w) * vc + bf2f(d.w) * vd);
        }
        for (; i < m0; ++i) {
            int s = ((const int*)r40)[i];
            float dv = DLUT(cnt[s]);
            ushort4 a = xsr[(size_t)s * 64 + lane];
            acc0.x += bf2f(a.x) * dv; acc0.y += bf2f(a.y) * dv;
            acc0.z += bf2f(a.z) * dv; acc0.w += bf2f(a.w) * dv;
        }
        for (; j + 4 <= m1; j += 4) {          // node1 remainder quads
            int4 b4 = r41[j >> 2];
            float ve = DLUT(cnt[b4.x]), vf = DLUT(cnt[b4.y]);
            float vg = DLUT(cnt[b4.z]), vh = DLUT(cnt[b4.w]);
            ushort4 e = xsr[(size_t)b4.x * 64 + lane];
            ushort4 f = xsr[(size_t)b4.y * 64 + lane];
            ushort4 g = xsr[(size_t)b4.z * 64 + lane];
            ushort4 h = xsr[(size_t)b4.w * 64 + lane];
            acc1.x += (bf2f(e.x) * ve + bf2f(f.x) * vf) + (bf2f(g.x) * vg + bf2f(h.x) * vh);
            acc1.y += (bf2f(e.y) * ve + bf2f(f.y) * vf) + (bf2f(g.y) * vg + bf2f(h.y) * vh);
            acc1.z += (bf2f(e.z) * ve + bf2f(f.z) * vf) + (bf2f(g.z) * vg + bf2f(h.z) * vh);
            acc1.w += (bf2f(e.w) * ve + bf2f(f.w) * vf) + (bf2f(g.w) * vg + bf2f(h.w) * vh);
        }
        for (; j < m1; ++j) {
            int s = ((const int*)r41)[j];
            float dv = DLUT(cnt[s]);
            ushort4 e = xsr[(size_t)s * 64 + lane];
            acc1.x += bf2f(e.x) * dv; acc1.y += bf2f(e.y) * dv;
            acc1.z += bf2f(e.z) * dv; acc1.w += bf2f(e.w) * dv;
        }

        unsigned short* yp0 = ylds + nl0 * NST;
        unsigned short* yp1 = ylds + nl1 * NST;
        yp0[0 * YST + lane] = f2bf(acc0.x * di0);
        yp0[1 * YST + lane] = f2bf(acc0.y * di0);
        yp0[2 * YST + lane] = f2bf(acc0.z * di0);
        yp0[3 * YST + lane] = f2bf(acc0.w * di0);
        yp1[0 * YST + lane] = f2bf(acc1.x * di1);
        yp1[1 * YST + lane] = f2bf(acc1.y * di1);
        yp1[2 * YST + lane] = f2bf(acc1.z * di1);
        yp1[3 * YST + lane] = f2bf(acc1.w * di1);
    }
    #undef DLUT
    __syncthreads();

    // ---------------- Phase B: node MFMA GEMM from LDS + xbp ----------------
    if (w * 16 >= nb) return;
    const int h = lane >> 4;          // quad
    const int m = lane & 15;
    const int nd = m >> 2, t = m & 3;

    const unsigned short* ylp[4];
    const unsigned short* xp[4];
    #pragma unroll
    for (int g = 0; g < 4; ++g) {
        int nl = w * 16 + g * 4 + nd;
        ylp[g] = ylds + nl * NST + t * YST;
        xp[g]  = xbp + (size_t)(base + nl) * 384 + t * 64;
    }

    f32x4 acc[4][4];
    #pragma unroll
    for (int g = 0; g < 4; ++g)
        #pragma unroll
        for (int ot = 0; ot < 4; ++ot)
            acc[g][ot] = (f32x4){0.f, 0.f, 0.f, 0.f};

    #pragma unroll
    for (int ki = 0; ki < 8; ++ki) {
        int b = ki >> 1;                       // 64-wide K-block
        int c0 = (ki & 1) * 32 + h * 8;        // offset within block
        int kof = ki * 32 + h * 8;
        bf16x8 bf[4];
        #pragma unroll
        for (int ot = 0; ot < 4; ++ot)
            bf[ot] = *(const bf16x8*)(Bt + (size_t)(ot * 16 + m) * 256 + kof);
        bf16x8 af[4];
        #pragma unroll
        for (int g = 0; g < 4; ++g) {
            const unsigned short* ap = (b == 0) ? (ylp[g] + c0)
                                                : (xp[g] + (b - 1) * 64 + c0);
            af[g] = *(const bf16x8*)ap;
        }
        #pragma unroll
        for (int g = 0; g < 4; ++g) {
            acc[g][0] = __builtin_amdgcn_mfma_f32_16x16x32_bf16(af[g], bf[0], acc[g][0], 0, 0, 0);
            acc[g][1] = __builtin_amdgcn_mfma_f32_16x16x32_bf16(af[g], bf[1], acc[g][1], 0, 0, 0);
            acc[g][2] = __builtin_amdgcn_mfma_f32_16x16x32_bf16(af[g], bf[2], acc[g][2], 0, 0, 0);
            acc[g][3] = __builtin_amdgcn_mfma_f32_16x16x32_bf16(af[g], bf[3], acc[g][3], 0, 0, 0);
        }
    }

    float4* out4 = (float4*)out;               // out[n][o][t], float4 over t
    #pragma unroll
    for (int g = 0; g < 4; ++g) {
        int nn = base + w * 16 + g * 4 + h;    // output node for this lane
        #pragma unroll
        for (int ot = 0; ot < 4; ++ot) {
            int o = ot * 16 + m;
            float bias = bb[o];
            out4[(size_t)nn * 64 + o] = make_float4(acc[g][ot][0] + bias,
                                                    acc[g][ot][1] + bias,
                                                    acc[g][ot][2] + bias,
                                                    acc[g][ot][3] + bias);
        }
    }
}

extern "C" void kernel_launch(void* const* d_in, const int* in_sizes, int n_in,
                              void* d_out, int out_size, void* d_ws, size_t ws_size,
                              hipStream_t stream) {
    const float* x  = (const float*)d_in[0];
    const int*   ei = (const int*)d_in[1];
    const float* Wg = (const float*)d_in[2];
    const float* bg = (const float*)d_in[3];
    const float* Wt = (const float*)d_in[4];
    const float* bt = (const float*)d_in[5];
    float* out = (float*)d_out;

    int N = in_sizes[0] / 256;   // 50000
    int E = in_sizes[1] / 2;     // 800000

    // workspace layout (256B-aligned):
    size_t off = 0;
    auto alloc = [&](size_t bytes) { size_t o = off; off += (bytes + 255) & ~(size_t)255; return o; };
    char* ws = (char*)d_ws;
    unsigned*       cnt  = (unsigned*)(ws + alloc((size_t)N * 4));
    unsigned short* Bt   = (unsigned short*)(ws + alloc(64 * 256 * 2));
    float*          bb   = (float*)(ws + alloc(64 * 4));
    int*            csr  = (int*)(ws + alloc((size_t)N * CAP * 4));
    ushort4*        xsr  = (ushort4*)(ws + alloc((size_t)N * 256 * 2));
    unsigned short* xbp  = (unsigned short*)(ws + alloc((size_t)N * 384 * 2));
    // total ~78 MB (yT deleted)

    int XB = (N + 3) / 4;                      // 12500 wave-per-node blocks
    zero_pack_kernel<<<XB, 256, 0, stream>>>(cnt, N, Wg, Wt, bg, bt, Bt, bb, x, xsr);
    int FB = (E + 2047) / 2048;                // 391 fill blocks (8 edges/thread)
    fill_xbp_kernel<<<FB + XB, 256, 0, stream>>>(ei, cnt, csr, E, x, xbp, N, FB);
    int GN = (N + NB - 1) / NB;                // 782 fused gather+node blocks
    gather_node_kernel<<<GN, 256, 0, stream>>>(xsr, csr, cnt, xbp, Bt, bb, out, N);
}

// Round 9
// 259.254 us; speedup vs baseline: 1.1452x; 1.1452x over previous
//
#include <hip/hip_runtime.h>
#include <math.h>

// STGCN layer: N=50000, E=800000, C_IN=C_OUT=64, T=4, KT=3.
// Round-16: gather+node fusion RESCUE. R8 failed on grid collapse (782 blocks
// = 3/CU, zero backfill rounds, 40KB LDS -> occ 19%, tail-dominated 138us),
// NOT on the fusion concept (FETCH 206MB proved the yT round-trip died).
// Fix: NB 64 -> 16. Grid 3125 blocks (12 rounds/CU backfill), LDS 13.3KB,
// phase A = 2 pairs/wave (split form was 1), phase B = wave 0 only.
//   zero_pack:   zero cnt; wave-per-node xsr bf16 [c][t] from x (cold);
//                block 0 packs Bt + bb.
//   fill_xbp:    fill role (8 edges/thread, 8 atomics in flight) || pack role
//                (x -> xbp bf16 [t][c] w/ guards; 90MB rides atomic shadow).
//   gather_node: block = 4 waves = 16 nodes. Phase A: wave gathers pairs
//                w, w+4 (8 gathers in flight, LDS-LUT dinv) -> ylds
//                [node][t][c] t-stride 72 ush (2 lanes/bank = free).
//                Phase B: wave 0 = 16-node MFMA GEMM (K-block 0 from LDS,
//                temporal K-blocks from xbp); waves 1-3 exit -> backfill.
// All dense math in bf16 MFMA w/ fp32 accum; aggregation in fp32.

#define CAP 64   // max bucket capacity; Poisson(16) max degree ~45

typedef __attribute__((ext_vector_type(8))) short bf16x8;   // 8 bf16 = 4 VGPRs
typedef __attribute__((ext_vector_type(4))) float f32x4;

__device__ __forceinline__ float bf2f(unsigned short u) {
    union { unsigned int i; float f; } c; c.i = ((unsigned int)u) << 16; return c.f;
}
__device__ __forceinline__ unsigned short f2bf(float f) {
    union { float f; unsigned int i; } c; c.f = f;
    return (unsigned short)((c.i + 0x7FFFu + ((c.i >> 16) & 1u)) >> 16);  // RNE
}

// Grid = wave-per-node (12500 blocks). Duties:
//  - thread gid < N: cnt[gid] = 0
//  - wave n: xsr[n][c] = bf16(x[n][c][t0..3]) (unscaled [c][t] ushort4)
//  - block 0: Bt[o][k] (k<64: Wg[k][o]; k=b*64+c: Wt[o][c][b-1]); bb=bg+bt
__global__ __launch_bounds__(256) void zero_pack_kernel(unsigned* __restrict__ cnt, int N,
                                                        const float* __restrict__ Wg,
                                                        const float* __restrict__ Wt,
                                                        const float* __restrict__ bg,
                                                        const float* __restrict__ bt,
                                                        unsigned short* __restrict__ Bt,
                                                        float* __restrict__ bb,
                                                        const float* __restrict__ x,
                                                        ushort4* __restrict__ xsr) {
    int gid = blockIdx.x * 256 + threadIdx.x;
    if (gid < N) cnt[gid] = 0u;
    int n = gid >> 6;
    int lane = threadIdx.x & 63;
    if (n < N) {
        float4 v = ((const float4*)x)[(size_t)n * 64 + lane];
        ushort4 sv;
        sv.x = f2bf(v.x); sv.y = f2bf(v.y);
        sv.z = f2bf(v.z); sv.w = f2bf(v.w);
        xsr[(size_t)n * 64 + lane] = sv;
    }
    if (blockIdx.x == 0) {
        for (int idx = threadIdx.x; idx < 64 * 256; idx += 256) {
            int o = idx >> 8, k = idx & 255;
            float w;
            if (k < 64) w = Wg[k * 64 + o];
            else { int b = k >> 6, c = k & 63; w = Wt[o * 192 + c * 3 + (b - 1)]; }
            Bt[idx] = f2bf(w);
        }
        if (threadIdx.x < 64) bb[threadIdx.x] = bg[threadIdx.x] + bt[threadIdx.x];
    }
}

// Fused fill + xbp pack. Block roles split by blockIdx:
//  [0, FB):       fill — 8 edges/thread, 8 independent atomics, 8 CSR stores.
//  [FB, FB+XB):   pack — wave per node, lane = channel; xbp [t][c] bf16 with
//                 zero guard rows at t=-1 and t=4 (x re-read is L3-hot).
__global__ __launch_bounds__(256) void fill_xbp_kernel(const int* __restrict__ ei,
                                                       unsigned* __restrict__ cnt,
                                                       int* __restrict__ csr, int E,
                                                       const float* __restrict__ x,
                                                       unsigned short* __restrict__ xbp,
                                                       int N, int FB) {
    if ((int)blockIdx.x < FB) {
        int t = blockIdx.x * 256 + threadIdx.x;
        int stride = FB * 256;
        int s[8]; int d[8]; unsigned slot[8];
        #pragma unroll
        for (int k = 0; k < 8; ++k) {
            int e = t + k * stride;
            bool v = (e < E);
            s[k] = v ? ei[e] : -1;       // row 0: src
            d[k] = v ? ei[E + e] : 0;    // row 1: dst
        }
        #pragma unroll
        for (int k = 0; k < 8; ++k)
            slot[k] = (s[k] >= 0) ? atomicAdd(&cnt[d[k]], 1u) : 0u;
        #pragma unroll
        for (int k = 0; k < 8; ++k)
            if (s[k] >= 0 && slot[k] < CAP)
                csr[(size_t)d[k] * CAP + slot[k]] = s[k];
    } else {
        int bid = blockIdx.x - FB;
        int n = (bid * 256 + threadIdx.x) >> 6;
        int lane = threadIdx.x & 63;
        if (n >= N) return;
        float4 v = ((const float4*)x)[(size_t)n * 64 + lane];
        unsigned short* xb = xbp + (size_t)n * 384;
        xb[lane]           = 0;            // t = -1 guard
        xb[64 + lane]      = f2bf(v.x);    // t = 0
        xb[128 + lane]     = f2bf(v.y);
        xb[192 + lane]     = f2bf(v.z);
        xb[256 + lane]     = f2bf(v.w);
        xb[320 + lane]     = 0;            // t = 4 guard
    }
}

#define LUTN 1024    // deg LUT entries; Poisson(16) max deg ~45, 1024 is safe
#define NB   16      // nodes per gather_node block (R8 lesson: keep grid big)
#define YST  72      // ushort stride per t-row (144B = 36dw = 4 mod 32 banks)
#define NST  (4*YST) // 288 ushort per node (576B, 16B-aligned)

// Fused gather + node GEMM. Block = 256 threads = 4 waves = NB=16 nodes.
// Phase A: wave w gathers node-pairs p = w, w+4 (2 pairs): lane = channel c
//   (ushort4 = t0..3); 2 int4 idx loads + 8 independent 512B gathers in
//   flight per iter; dinv via LDS LUT; result -> ylds.
// Phase B: wave 0 = all 16 nodes: 4 groups x 4 nodes, K=256, o=64.
//   A[(n,t)][k]: k<64 -> ylds[nl][t][k] (ds_read_b128, 2-way=free);
//   k=b*64+c -> xbp[n][t+b-1][c] global (guarded rows).
//   B-frag from Bt[o][k] (L2-hot). Waves 1-3 exit after barrier -> backfill.
__global__ __launch_bounds__(256) void gather_node_kernel(const ushort4* __restrict__ xsr,
                                                          const int* __restrict__ csr,
                                                          const unsigned* __restrict__ cnt,
                                                          const unsigned short* __restrict__ xbp,
                                                          const unsigned short* __restrict__ Bt,
                                                          const float* __restrict__ bb,
                                                          float* __restrict__ out, int N) {
    __shared__ float lut[LUTN];
    __shared__ unsigned short ylds[NB * NST];   // 9.2 KB (+4KB lut = 13.3KB)
    for (int i = threadIdx.x; i < LUTN; i += 256)
        lut[i] = rsqrtf((float)i + 1.0f);
    __syncthreads();

    const int w = threadIdx.x >> 6;
    const int lane = threadIdx.x & 63;
    const int base = blockIdx.x * NB;
    int nb = N - base; if (nb > NB) nb = NB;    // N % 16 == 0 -> nb = 16
    const int npairs = nb >> 1;

    #define DLUT(dv) lut[(dv) < LUTN ? (dv) : LUTN - 1]

    // ---------------- Phase A: gather into LDS ------------------------------
    for (int p = w; p < npairs; p += 4) {
        int nl0 = p * 2, nl1 = nl0 + 1;
        int n0 = base + nl0, n1 = n0 + 1;
        unsigned deg0 = cnt[n0], deg1 = cnt[n1];
        int m0 = (int)deg0; if (m0 > CAP) m0 = CAP;
        int m1 = (int)deg1; if (m1 > CAP) m1 = CAP;
        const int4* r40 = (const int4*)(csr + (size_t)n0 * CAP);
        const int4* r41 = (const int4*)(csr + (size_t)n1 * CAP);
        float di0 = DLUT(deg0), di1 = DLUT(deg1);
        ushort4 s0 = xsr[(size_t)n0 * 64 + lane];
        ushort4 s1 = xsr[(size_t)n1 * 64 + lane];
        float4 acc0 = make_float4(bf2f(s0.x) * di0, bf2f(s0.y) * di0,
                                  bf2f(s0.z) * di0, bf2f(s0.w) * di0);
        float4 acc1 = make_float4(bf2f(s1.x) * di1, bf2f(s1.y) * di1,
                                  bf2f(s1.z) * di1, bf2f(s1.w) * di1);

        int mc = (m0 < m1 ? m0 : m1) & ~3;
        int i = 0;
        for (; i < mc; i += 4) {               // 8 gathers in flight
            int4 a4 = r40[i >> 2];
            int4 b4 = r41[i >> 2];
            float va = DLUT(cnt[a4.x]), vb = DLUT(cnt[a4.y]);
            float vc = DLUT(cnt[a4.z]), vd = DLUT(cnt[a4.w]);
            float ve = DLUT(cnt[b4.x]), vf = DLUT(cnt[b4.y]);
            float vg = DLUT(cnt[b4.z]), vh = DLUT(cnt[b4.w]);
            ushort4 a = xsr[(size_t)a4.x * 64 + lane];
            ushort4 b = xsr[(size_t)a4.y * 64 + lane];
            ushort4 c = xsr[(size_t)a4.z * 64 + lane];
            ushort4 d = xsr[(size_t)a4.w * 64 + lane];
            ushort4 e = xsr[(size_t)b4.x * 64 + lane];
            ushort4 f = xsr[(size_t)b4.y * 64 + lane];
            ushort4 g = xsr[(size_t)b4.z * 64 + lane];
            ushort4 h = xsr[(size_t)b4.w * 64 + lane];
            acc0.x += (bf2f(a.x) * va + bf2f(b.x) * vb) + (bf2f(c.x) * vc + bf2f(d.x) * vd);
            acc0.y += (bf2f(a.y) * va + bf2f(b.y) * vb) + (bf2f(c.y) * vc + bf2f(d.y) * vd);
            acc0.z += (bf2f(a.z) * va + bf2f(b.z) * vb) + (bf2f(c.z) * vc + bf2f(d.z) * vd);
            acc0.w += (bf2f(a.w) * va + bf2f(b.w) * vb) + (bf2f(c.w) * vc + bf2f(d.w) * vd);
            acc1.x += (bf2f(e.x) * ve + bf2f(f.x) * vf) + (bf2f(g.x) * vg + bf2f(h.x) * vh);
            acc1.y += (bf2f(e.y) * ve + bf2f(f.y) * vf) + (bf2f(g.y) * vg + bf2f(h.y) * vh);
            acc1.z += (bf2f(e.z) * ve + bf2f(f.z) * vf) + (bf2f(g.z) * vg + bf2f(h.z) * vh);
            acc1.w += (bf2f(e.w) * ve + bf2f(f.w) * vf) + (bf2f(g.w) * vg + bf2f(h.w) * vh);
        }
        int j = i;
        for (; i + 4 <= m0; i += 4) {          // node0 remainder quads
            int4 a4 = r40[i >> 2];
            float va = DLUT(cnt[a4.x]), vb = DLUT(cnt[a4.y]);
            float vc = DLUT(cnt[a4.z]), vd = DLUT(cnt[a4.w]);
            ushort4 a = xsr[(size_t)a4.x * 64 + lane];
            ushort4 b = xsr[(size_t)a4.y * 64 + lane];
            ushort4 c = xsr[(size_t)a4.z * 64 + lane];
            ushort4 d = xsr[(size_t)a4.w * 64 + lane];
            acc0.x += (bf2f(a.x) * va + bf2f(b.x) * vb) + (bf2f(c.x) * vc + bf2f(d.x) * vd);
            acc0.y += (bf2f(a.y) * va + bf2f(b.y) * vb) + (bf2f(c.y) * vc + bf2f(d.y) * vd);
            acc0.z += (bf2f(a.z) * va + bf2f(b.z) * vb) + (bf2f(c.z) * vc + bf2f(d.z) * vd);
            acc0.w += (bf2f(a.w) * va + bf2f(b.w) * vb) + (bf2f(c.w) * vc + bf2f(d.w) * vd);
        }
        for (; i < m0; ++i) {
            int s = ((const int*)r40)[i];
            float dv = DLUT(cnt[s]);
            ushort4 a = xsr[(size_t)s * 64 + lane];
            acc0.x += bf2f(a.x) * dv; acc0.y += bf2f(a.y) * dv;
            acc0.z += bf2f(a.z) * dv; acc0.w += bf2f(a.w) * dv;
        }
        for (; j + 4 <= m1; j += 4) {          // node1 remainder quads
            int4 b4 = r41[j >> 2];
            float ve = DLUT(cnt[b4.x]), vf = DLUT(cnt[b4.y]);
            float vg = DLUT(cnt[b4.z]), vh = DLUT(cnt[b4.w]);
            ushort4 e = xsr[(size_t)b4.x * 64 + lane];
            ushort4 f = xsr[(size_t)b4.y * 64 + lane];
            ushort4 g = xsr[(size_t)b4.z * 64 + lane];
            ushort4 h = xsr[(size_t)b4.w * 64 + lane];
            acc1.x += (bf2f(e.x) * ve + bf2f(f.x) * vf) + (bf2f(g.x) * vg + bf2f(h.x) * vh);
            acc1.y += (bf2f(e.y) * ve + bf2f(f.y) * vf) + (bf2f(g.y) * vg + bf2f(h.y) * vh);
            acc1.z += (bf2f(e.z) * ve + bf2f(f.z) * vf) + (bf2f(g.z) * vg + bf2f(h.z) * vh);
            acc1.w += (bf2f(e.w) * ve + bf2f(f.w) * vf) + (bf2f(g.w) * vg + bf2f(h.w) * vh);
        }
        for (; j < m1; ++j) {
            int s = ((const int*)r41)[j];
            float dv = DLUT(cnt[s]);
            ushort4 e = xsr[(size_t)s * 64 + lane];
            acc1.x += bf2f(e.x) * dv; acc1.y += bf2f(e.y) * dv;
            acc1.z += bf2f(e.z) * dv; acc1.w += bf2f(e.w) * dv;
        }

        unsigned short* yp0 = ylds + nl0 * NST;
        unsigned short* yp1 = ylds + nl1 * NST;
        yp0[0 * YST + lane] = f2bf(acc0.x * di0);
        yp0[1 * YST + lane] = f2bf(acc0.y * di0);
        yp0[2 * YST + lane] = f2bf(acc0.z * di0);
        yp0[3 * YST + lane] = f2bf(acc0.w * di0);
        yp1[0 * YST + lane] = f2bf(acc1.x * di1);
        yp1[1 * YST + lane] = f2bf(acc1.y * di1);
        yp1[2 * YST + lane] = f2bf(acc1.z * di1);
        yp1[3 * YST + lane] = f2bf(acc1.w * di1);
    }
    #undef DLUT
    __syncthreads();

    // ---------------- Phase B: node MFMA GEMM from LDS + xbp (wave 0) -------
    if (w * 16 >= nb) return;                  // waves 1-3 exit -> backfill
    const int h = lane >> 4;          // quad
    const int m = lane & 15;
    const int nd = m >> 2, t = m & 3;

    const unsigned short* ylp[4];
    const unsigned short* xp[4];
    #pragma unroll
    for (int g = 0; g < 4; ++g) {
        int nl = w * 16 + g * 4 + nd;
        ylp[g] = ylds + nl * NST + t * YST;
        xp[g]  = xbp + (size_t)(base + nl) * 384 + t * 64;
    }

    f32x4 acc[4][4];
    #pragma unroll
    for (int g = 0; g < 4; ++g)
        #pragma unroll
        for (int ot = 0; ot < 4; ++ot)
            acc[g][ot] = (f32x4){0.f, 0.f, 0.f, 0.f};

    #pragma unroll
    for (int ki = 0; ki < 8; ++ki) {
        int b = ki >> 1;                       // 64-wide K-block
        int c0 = (ki & 1) * 32 + h * 8;        // offset within block
        int kof = ki * 32 + h * 8;
        bf16x8 bf[4];
        #pragma unroll
        for (int ot = 0; ot < 4; ++ot)
            bf[ot] = *(const bf16x8*)(Bt + (size_t)(ot * 16 + m) * 256 + kof);
        bf16x8 af[4];
        #pragma unroll
        for (int g = 0; g < 4; ++g) {
            const unsigned short* ap = (b == 0) ? (ylp[g] + c0)
                                                : (xp[g] + (b - 1) * 64 + c0);
            af[g] = *(const bf16x8*)ap;
        }
        #pragma unroll
        for (int g = 0; g < 4; ++g) {
            acc[g][0] = __builtin_amdgcn_mfma_f32_16x16x32_bf16(af[g], bf[0], acc[g][0], 0, 0, 0);
            acc[g][1] = __builtin_amdgcn_mfma_f32_16x16x32_bf16(af[g], bf[1], acc[g][1], 0, 0, 0);
            acc[g][2] = __builtin_amdgcn_mfma_f32_16x16x32_bf16(af[g], bf[2], acc[g][2], 0, 0, 0);
            acc[g][3] = __builtin_amdgcn_mfma_f32_16x16x32_bf16(af[g], bf[3], acc[g][3], 0, 0, 0);
        }
    }

    float4* out4 = (float4*)out;               // out[n][o][t], float4 over t
    #pragma unroll
    for (int g = 0; g < 4; ++g) {
        int nn = base + w * 16 + g * 4 + h;    // output node for this lane
        #pragma unroll
        for (int ot = 0; ot < 4; ++ot) {
            int o = ot * 16 + m;
            float bias = bb[o];
            out4[(size_t)nn * 64 + o] = make_float4(acc[g][ot][0] + bias,
                                                    acc[g][ot][1] + bias,
                                                    acc[g][ot][2] + bias,
                                                    acc[g][ot][3] + bias);
        }
    }
}

extern "C" void kernel_launch(void* const* d_in, const int* in_sizes, int n_in,
                              void* d_out, int out_size, void* d_ws, size_t ws_size,
                              hipStream_t stream) {
    const float* x  = (const float*)d_in[0];
    const int*   ei = (const int*)d_in[1];
    const float* Wg = (const float*)d_in[2];
    const float* bg = (const float*)d_in[3];
    const float* Wt = (const float*)d_in[4];
    const float* bt = (const float*)d_in[5];
    float* out = (float*)d_out;

    int N = in_sizes[0] / 256;   // 50000
    int E = in_sizes[1] / 2;     // 800000

    // workspace layout (256B-aligned):
    size_t off = 0;
    auto alloc = [&](size_t bytes) { size_t o = off; off += (bytes + 255) & ~(size_t)255; return o; };
    char* ws = (char*)d_ws;
    unsigned*       cnt  = (unsigned*)(ws + alloc((size_t)N * 4));
    unsigned short* Bt   = (unsigned short*)(ws + alloc(64 * 256 * 2));
    float*          bb   = (float*)(ws + alloc(64 * 4));
    int*            csr  = (int*)(ws + alloc((size_t)N * CAP * 4));
    ushort4*        xsr  = (ushort4*)(ws + alloc((size_t)N * 256 * 2));
    unsigned short* xbp  = (unsigned short*)(ws + alloc((size_t)N * 384 * 2));
    // total ~78 MB (yT deleted)

    int XB = (N + 3) / 4;                      // 12500 wave-per-node blocks
    zero_pack_kernel<<<XB, 256, 0, stream>>>(cnt, N, Wg, Wt, bg, bt, Bt, bb, x, xsr);
    int FB = (E + 2047) / 2048;                // 391 fill blocks (8 edges/thread)
    fill_xbp_kernel<<<FB + XB, 256, 0, stream>>>(ei, cnt, csr, E, x, xbp, N, FB);
    int GN = (N + NB - 1) / NB;                // 3125 fused gather+node blocks
    gather_node_kernel<<<GN, 256, 0, stream>>>(xsr, csr, cnt, xbp, Bt, bb, out, N);
}